// Round 2
// 365.801 us; speedup vs baseline: 1.0257x; 1.0257x over previous
//
#include <hip/hip_runtime.h>
#include <hip/hip_bf16.h>
#include <stdint.h>

#define NNODES 100000
#define DF 64
#define NEDGES 1600000
#define ND (NNODES * DF)     // 6,400,000
#define BKT 100              // targets per bucket
#define NBUCK 1000           // BKT*NBUCK == NNODES
#define CHUNK 128            // edges per wave in agg_k
#define NCHUNK (NEDGES / CHUNK)   // 12500

// ---------- helpers ----------
static __device__ __forceinline__ float bf2f(unsigned short u) {
    union { uint32_t i; float f; } c; c.i = ((uint32_t)u) << 16; return c.f;
}
static __device__ __forceinline__ void unpack2(uint32_t u, float& lo, float& hi) {
    union { uint32_t i; float f; } a, b;
    a.i = u << 16; b.i = u & 0xFFFF0000u;
    lo = a.f; hi = b.f;
}
static __device__ __forceinline__ uint32_t pkbf2(float lo, float hi) {
    union { __hip_bfloat16 b; unsigned short u; } a, b2;
    a.b = __float2bfloat16(lo); b2.b = __float2bfloat16(hi);
    return ((uint32_t)b2.u << 16) | (uint32_t)a.u;
}

// ---------- dtype detector: flags[0]=bf16?, flags[1]=int64? ----------
__global__ void detect_k(const unsigned short* __restrict__ x,
                         const unsigned int* __restrict__ ei,
                         int* __restrict__ flags) {
    __shared__ int cnt_sane, cnt_odd_nz;
    if (threadIdx.x == 0) { cnt_sane = 0; cnt_odd_nz = 0; }
    __syncthreads();
    unsigned short s = x[threadIdx.x * 2];
    unsigned short m = s & 0x7FFF;
    if (m < 0x0080 || (m >= 0x3000 && m <= 0x4200)) atomicAdd(&cnt_sane, 1);
    if (threadIdx.x < 64) {
        if (ei[threadIdx.x * 2 + 1] != 0u) atomicAdd(&cnt_odd_nz, 1);
    }
    __syncthreads();
    if (threadIdx.x == 0) {
        flags[0] = (cnt_sane >= 192) ? 1 : 0;
        flags[1] = (cnt_odd_nz == 0) ? 1 : 0;
    }
}

// ---------- weight canonicalization -> fp32 ----------
__global__ void wconv_k(const int* __restrict__ flags,
                        const void* __restrict__ Wm, const void* __restrict__ Wu,
                        const void* __restrict__ bm, const void* __restrict__ bu,
                        const void* __restrict__ ga, const void* __restrict__ be,
                        float* __restrict__ WfM, float* __restrict__ WfU,
                        float* __restrict__ prm) {
    const int bf = flags[0];
    int i = blockIdx.x * 256 + threadIdx.x;
    if (i < 16384) {
        const void* src = (i < 8192) ? Wm : Wu;
        float* dst = (i < 8192) ? WfM : WfU;
        int ii = i & 8191, j = ii >> 6, k = ii & 63;
        int si = (j & 63) * 128 + ((j >> 6) ? 64 : 0) + k;
        dst[ii] = bf ? bf2f(((const unsigned short*)src)[si]) : ((const float*)src)[si];
    } else if (i < 16384 + 256) {
        int t = i - 16384, which = t >> 6, k = t & 63;
        const void* p = (which == 0) ? bm : (which == 1) ? bu : (which == 2) ? ga : be;
        prm[t] = bf ? bf2f(((const unsigned short*)p)[k]) : ((const float*)p)[k];
    }
}

// ---------- projection: Ps = x@Wm_s^T ; Pt = x@Wm_t^T + b_msg  (bf16 out) ----------
// lane = node. Full x-row in registers; weights broadcast from LDS per output dim.
__global__ __launch_bounds__(256, 2) void proj_k(const int* __restrict__ flags,
                                                 const void* __restrict__ xv,
                                                 const float* __restrict__ WfM,
                                                 const float* __restrict__ prm,
                                                 __hip_bfloat16* __restrict__ Ps,
                                                 __hip_bfloat16* __restrict__ Pt) {
    __shared__ float wlds[8192];
    __shared__ float blds[64];
    for (int i = threadIdx.x; i < 8192; i += 256) wlds[i] = WfM[i];
    if (threadIdx.x < 64) blds[threadIdx.x] = prm[threadIdx.x];
    __syncthreads();
    const int bf = flags[0];
    const int n = blockIdx.x * 256 + threadIdx.x;
    if (n >= NNODES) return;

    float xr[64];
    if (bf) {
        const uint4* xw = (const uint4*)((const unsigned short*)xv + (size_t)n * DF);
        #pragma unroll
        for (int q = 0; q < 8; ++q) {
            uint4 v = xw[q];
            unpack2(v.x, xr[8*q+0], xr[8*q+1]);
            unpack2(v.y, xr[8*q+2], xr[8*q+3]);
            unpack2(v.z, xr[8*q+4], xr[8*q+5]);
            unpack2(v.w, xr[8*q+6], xr[8*q+7]);
        }
    } else {
        const float4* xf = (const float4*)((const float*)xv + (size_t)n * DF);
        #pragma unroll
        for (int q = 0; q < 16; ++q) {
            float4 v = xf[q];
            xr[4*q+0] = v.x; xr[4*q+1] = v.y; xr[4*q+2] = v.z; xr[4*q+3] = v.w;
        }
    }

    uint32_t pso[32], pto[32];
    #pragma unroll
    for (int jp = 0; jp < 32; ++jp) {
        float sv0, sv1, tv0, tv1;
        #pragma unroll
        for (int h = 0; h < 2; ++h) {
            const int j = 2*jp + h;
            const float4* ws4 = (const float4*)(wlds + j * 64);
            const float4* wt4 = (const float4*)(wlds + (64 + j) * 64);
            float a0=0.f,a1=0.f,a2=0.f,a3=0.f,b0=0.f,b1=0.f,b2=0.f,b3=0.f;
            #pragma unroll
            for (int k = 0; k < 16; ++k) {
                float4 w1 = ws4[k];
                float4 w2 = wt4[k];
                a0 = fmaf(xr[4*k+0], w1.x, a0);
                a1 = fmaf(xr[4*k+1], w1.y, a1);
                a2 = fmaf(xr[4*k+2], w1.z, a2);
                a3 = fmaf(xr[4*k+3], w1.w, a3);
                b0 = fmaf(xr[4*k+0], w2.x, b0);
                b1 = fmaf(xr[4*k+1], w2.y, b1);
                b2 = fmaf(xr[4*k+2], w2.z, b2);
                b3 = fmaf(xr[4*k+3], w2.w, b3);
            }
            float sv = (a0+a1)+(a2+a3);
            float tv = (b0+b1)+(b2+b3) + blds[j];
            if (h == 0) { sv0 = sv; tv0 = tv; } else { sv1 = sv; tv1 = tv; }
        }
        pso[jp] = pkbf2(sv0, sv1);
        pto[jp] = pkbf2(tv0, tv1);
    }
    uint4* po = (uint4*)((unsigned short*)Ps + (size_t)n * DF);
    uint4* pt = (uint4*)((unsigned short*)Pt + (size_t)n * DF);
    #pragma unroll
    for (int q = 0; q < 8; ++q) {
        po[q] = make_uint4(pso[4*q+0], pso[4*q+1], pso[4*q+2], pso[4*q+3]);
        pt[q] = make_uint4(pto[4*q+0], pto[4*q+1], pto[4*q+2], pto[4*q+3]);
    }
}

// ---------- bucket histogram (LDS pre-aggregated) ----------
__global__ __launch_bounds__(256) void bhist_k(const int* __restrict__ flags,
                                               const int* __restrict__ ei,
                                               int* __restrict__ BktCnt) {
    __shared__ int h[NBUCK];
    const int i64 = flags[1];
    for (int i = threadIdx.x; i < NBUCK; i += 256) h[i] = 0;
    __syncthreads();
    int stride = gridDim.x * 256;
    for (int e = blockIdx.x * 256 + threadIdx.x; e < NEDGES; e += stride) {
        int tgt = i64 ? ei[4*e + 2] : ei[2*e + 1];
        if ((unsigned)tgt < NNODES) atomicAdd(&h[tgt / BKT], 1);
    }
    __syncthreads();
    for (int b = threadIdx.x; b < NBUCK; b += 256)
        if (h[b]) atomicAdd(BktCnt + b, h[b]);
}

// ---------- scan of 1000 bucket counts ----------
__global__ __launch_bounds__(1024) void bscan_k(const int* __restrict__ BktCnt,
                                                int* __restrict__ BktOff,
                                                int* __restrict__ BktCur) {
    __shared__ int lds[1024];
    int t = threadIdx.x;
    int c = (t < NBUCK) ? BktCnt[t] : 0;
    lds[t] = c;
    __syncthreads();
    for (int off = 1; off < 1024; off <<= 1) {
        int add = (t >= off) ? lds[t - off] : 0;
        __syncthreads();
        lds[t] += add;
        __syncthreads();
    }
    if (t < NBUCK) {
        int ex = lds[t] - c;
        BktOff[t] = ex;
        BktCur[t] = ex;
    }
    if (t == NBUCK - 1) BktOff[NBUCK] = lds[t];
}

// ---------- bucket fill: two-pass binning, packed (tl<<24 | src) ----------
__global__ __launch_bounds__(256) void bfill_k(const int* __restrict__ flags,
                                               const int* __restrict__ ei,
                                               int* __restrict__ BktCur,
                                               int* __restrict__ BktE) {
    __shared__ int h[NBUCK], h2[NBUCK], basee[NBUCK];
    const int i64 = flags[1];
    for (int i = threadIdx.x; i < NBUCK; i += 256) { h[i] = 0; h2[i] = 0; }
    __syncthreads();
    const int stride = gridDim.x * 256;
    for (int e = blockIdx.x * 256 + threadIdx.x; e < NEDGES; e += stride) {
        int tgt = i64 ? ei[4*e + 2] : ei[2*e + 1];
        if ((unsigned)tgt < NNODES) atomicAdd(&h[tgt / BKT], 1);
    }
    __syncthreads();
    for (int b = threadIdx.x; b < NBUCK; b += 256)
        if (h[b]) basee[b] = atomicAdd(BktCur + b, h[b]);
    __syncthreads();
    for (int e = blockIdx.x * 256 + threadIdx.x; e < NEDGES; e += stride) {
        int src, tgt;
        if (i64) { src = ei[4*e]; tgt = ei[4*e + 2]; }
        else     { src = ei[2*e]; tgt = ei[2*e + 1]; }
        if ((unsigned)tgt >= NNODES) continue;
        int b = tgt / BKT;
        int tl = tgt - b * BKT;
        int r = atomicAdd(&h2[b], 1);
        BktE[basee[b] + r] = (tl << 24) | (src & 0xFFFFFF);
    }
}

// ---------- per-bucket counting sort by target -> CsrSrc + Row ----------
__global__ __launch_bounds__(256) void tsort_k(const int* __restrict__ BktOff,
                                               const int* __restrict__ BktE,
                                               int* __restrict__ CsrSrc,
                                               int* __restrict__ Row) {
    __shared__ int oc[128], excl[128], cur[128];
    const int tid = threadIdx.x;
    const int b = blockIdx.x;
    const int s = BktOff[b], e = BktOff[b + 1];
    const int n = e - s;
    if (tid < 128) { oc[tid] = 0; }
    __syncthreads();
    for (int i = tid; i < n; i += 256)
        atomicAdd(&oc[((unsigned)BktE[s + i]) >> 24], 1);
    __syncthreads();
    if (tid < 128) excl[tid] = (tid > 0) ? oc[tid - 1] : 0;
    __syncthreads();
    for (int off = 1; off < 128; off <<= 1) {
        int add = (tid >= off && tid < 128) ? excl[tid - off] : 0;
        __syncthreads();
        if (tid < 128) excl[tid] += add;
        __syncthreads();
    }
    if (tid < BKT) {
        Row[b * BKT + tid] = s + excl[tid];
        cur[tid] = excl[tid];
    }
    if (b == 0 && tid == 0) Row[NNODES] = NEDGES;
    __syncthreads();
    for (int i = tid; i < n; i += 256) {
        int v = BktE[s + i];
        int tl = ((unsigned)v) >> 24;
        int p = atomicAdd(&cur[tl], 1);
        CsrSrc[s + p] = v & 0xFFFFFF;
    }
}

// ---------- aggregation: target-aligned chunks, register accumulate ----------
__global__ __launch_bounds__(256) void agg_k(const __hip_bfloat16* __restrict__ Ps,
                                             const __hip_bfloat16* __restrict__ Pt,
                                             const int* __restrict__ Row,
                                             const int* __restrict__ CsrSrc,
                                             __hip_bfloat16* __restrict__ Msg) {
    const int lane = threadIdx.x & 63;
    const int wib = __builtin_amdgcn_readfirstlane(threadIdx.x >> 6);
    const int w = blockIdx.x * 4 + wib;
    if (w >= NCHUNK) return;
    const int eA = w * CHUNK;
    const int hiB = (w == NCHUNK - 1) ? (NEDGES + 1) : (eA + CHUNK);

    int lo = 0, hi = NNODES + 1;
    while (lo < hi) { int mid = (lo + hi) >> 1; if (Row[mid] >= eA) hi = mid; else lo = mid + 1; }
    const int t_lo = lo;
    lo = t_lo; hi = NNODES + 1;
    while (lo < hi) { int mid = (lo + hi) >> 1; if (Row[mid] >= hiB) hi = mid; else lo = mid + 1; }
    int t_hi = lo;
    if (t_hi > NNODES) t_hi = NNODES;

    const unsigned short* Ps16 = (const unsigned short*)Ps;
    const unsigned short* Pt16 = (const unsigned short*)Pt;

    for (int t = t_lo; t < t_hi; ++t) {
        const int segS = Row[t], segE = Row[t + 1];
        const int deg = segE - segS;
        float pt = bf2f(Pt16[(size_t)t * DF + lane]);
        float macc = 0.f;
        int i = segS;
        for (; i + 8 <= segE; i += 8) {
            int s0 = CsrSrc[i+0], s1 = CsrSrc[i+1], s2 = CsrSrc[i+2], s3 = CsrSrc[i+3];
            int s4 = CsrSrc[i+4], s5 = CsrSrc[i+5], s6 = CsrSrc[i+6], s7 = CsrSrc[i+7];
            if ((unsigned)s0 >= NNODES) s0 = 0;
            if ((unsigned)s1 >= NNODES) s1 = 0;
            if ((unsigned)s2 >= NNODES) s2 = 0;
            if ((unsigned)s3 >= NNODES) s3 = 0;
            if ((unsigned)s4 >= NNODES) s4 = 0;
            if ((unsigned)s5 >= NNODES) s5 = 0;
            if ((unsigned)s6 >= NNODES) s6 = 0;
            if ((unsigned)s7 >= NNODES) s7 = 0;
            float p0 = bf2f(Ps16[(size_t)s0 * DF + lane]);
            float p1 = bf2f(Ps16[(size_t)s1 * DF + lane]);
            float p2 = bf2f(Ps16[(size_t)s2 * DF + lane]);
            float p3 = bf2f(Ps16[(size_t)s3 * DF + lane]);
            float p4 = bf2f(Ps16[(size_t)s4 * DF + lane]);
            float p5 = bf2f(Ps16[(size_t)s5 * DF + lane]);
            float p6 = bf2f(Ps16[(size_t)s6 * DF + lane]);
            float p7 = bf2f(Ps16[(size_t)s7 * DF + lane]);
            macc += fmaxf(p0 + pt, 0.f) + fmaxf(p1 + pt, 0.f)
                  + fmaxf(p2 + pt, 0.f) + fmaxf(p3 + pt, 0.f)
                  + fmaxf(p4 + pt, 0.f) + fmaxf(p5 + pt, 0.f)
                  + fmaxf(p6 + pt, 0.f) + fmaxf(p7 + pt, 0.f);
        }
        for (; i < segE; ++i) {
            int s0 = CsrSrc[i];
            if ((unsigned)s0 >= NNODES) s0 = 0;
            macc += fmaxf(bf2f(Ps16[(size_t)s0 * DF + lane]) + pt, 0.f);
        }
        float mval = (deg > 0) ? (macc / (float)deg) : 0.f;
        Msg[(size_t)t * DF + lane] = __float2bfloat16(mval);
    }
}

// ---------- update + residual + LayerNorm (lane = node, row in registers) ----------
__global__ __launch_bounds__(256, 2) void upd_k(const int* __restrict__ flags,
                                                const void* __restrict__ xv,
                                                const __hip_bfloat16* __restrict__ Msg,
                                                const float* __restrict__ WfU,
                                                const float* __restrict__ prm,
                                                void* __restrict__ outv) {
    __shared__ float wlds[8192];
    __shared__ float plds[192];   // [0:64)=b_upd, [64:128)=gamma, [128:192)=beta
    for (int i = threadIdx.x; i < 8192; i += 256) wlds[i] = WfU[i];
    if (threadIdx.x < 192) plds[threadIdx.x] = prm[64 + threadIdx.x];
    __syncthreads();
    const int bf = flags[0];
    const int n = blockIdx.x * 256 + threadIdx.x;
    if (n >= NNODES) return;

    float xr[64], mr[64];
    if (bf) {
        const uint4* xw = (const uint4*)((const unsigned short*)xv + (size_t)n * DF);
        #pragma unroll
        for (int q = 0; q < 8; ++q) {
            uint4 v = xw[q];
            unpack2(v.x, xr[8*q+0], xr[8*q+1]);
            unpack2(v.y, xr[8*q+2], xr[8*q+3]);
            unpack2(v.z, xr[8*q+4], xr[8*q+5]);
            unpack2(v.w, xr[8*q+6], xr[8*q+7]);
        }
    } else {
        const float4* xf = (const float4*)((const float*)xv + (size_t)n * DF);
        #pragma unroll
        for (int q = 0; q < 16; ++q) {
            float4 v = xf[q];
            xr[4*q+0] = v.x; xr[4*q+1] = v.y; xr[4*q+2] = v.z; xr[4*q+3] = v.w;
        }
    }
    {
        const uint4* mw = (const uint4*)((const unsigned short*)Msg + (size_t)n * DF);
        #pragma unroll
        for (int q = 0; q < 8; ++q) {
            uint4 v = mw[q];
            unpack2(v.x, mr[8*q+0], mr[8*q+1]);
            unpack2(v.y, mr[8*q+2], mr[8*q+3]);
            unpack2(v.z, mr[8*q+4], mr[8*q+5]);
            unpack2(v.w, mr[8*q+6], mr[8*q+7]);
        }
    }

    float rr[64];
    float s = 0.f, s2 = 0.f;
    #pragma unroll
    for (int j = 0; j < 64; ++j) {
        const float4* wx4 = (const float4*)(wlds + j * 64);
        const float4* wm4 = (const float4*)(wlds + (64 + j) * 64);
        float a0=0.f,a1=0.f,a2=0.f,a3=0.f,b0=0.f,b1=0.f,b2=0.f,b3=0.f;
        #pragma unroll
        for (int k = 0; k < 16; ++k) {
            float4 w1 = wx4[k];
            float4 w2 = wm4[k];
            a0 = fmaf(xr[4*k+0], w1.x, a0);
            a1 = fmaf(xr[4*k+1], w1.y, a1);
            a2 = fmaf(xr[4*k+2], w1.z, a2);
            a3 = fmaf(xr[4*k+3], w1.w, a3);
            b0 = fmaf(mr[4*k+0], w2.x, b0);
            b1 = fmaf(mr[4*k+1], w2.y, b1);
            b2 = fmaf(mr[4*k+2], w2.z, b2);
            b3 = fmaf(mr[4*k+3], w2.w, b3);
        }
        float u = fmaxf((a0+a1)+(a2+a3) + (b0+b1)+(b2+b3) + plds[j], 0.f);
        float r = u + xr[j];
        rr[j] = r;
        s += r;
        s2 = fmaf(r, r, s2);
    }

    float mu  = s  * (1.0f / 64.0f);
    float var = fmaxf(s2 * (1.0f / 64.0f) - mu * mu, 0.f);
    float kv  = rsqrtf(var + 1e-5f);

    if (bf) {
        uint32_t ob[32];
        #pragma unroll
        for (int jp = 0; jp < 32; ++jp) {
            float o0 = (rr[2*jp+0] - mu) * kv * plds[64 + 2*jp+0] + plds[128 + 2*jp+0];
            float o1 = (rr[2*jp+1] - mu) * kv * plds[64 + 2*jp+1] + plds[128 + 2*jp+1];
            ob[jp] = pkbf2(o0, o1);
        }
        uint4* po = (uint4*)((unsigned short*)outv + (size_t)n * DF);
        #pragma unroll
        for (int q = 0; q < 8; ++q)
            po[q] = make_uint4(ob[4*q+0], ob[4*q+1], ob[4*q+2], ob[4*q+3]);
    } else {
        float4* po = (float4*)((float*)outv + (size_t)n * DF);
        #pragma unroll
        for (int q = 0; q < 16; ++q) {
            float4 v;
            v.x = (rr[4*q+0] - mu) * kv * plds[64 + 4*q+0] + plds[128 + 4*q+0];
            v.y = (rr[4*q+1] - mu) * kv * plds[64 + 4*q+1] + plds[128 + 4*q+1];
            v.z = (rr[4*q+2] - mu) * kv * plds[64 + 4*q+2] + plds[128 + 4*q+2];
            v.w = (rr[4*q+3] - mu) * kv * plds[64 + 4*q+3] + plds[128 + 4*q+3];
            po[q] = v;
        }
    }
}

extern "C" void kernel_launch(void* const* d_in, const int* in_sizes, int n_in,
                              void* d_out, int out_size, void* d_ws, size_t ws_size,
                              hipStream_t stream) {
    const void* x  = d_in[0];
    const int*  ei = (const int*)d_in[1];
    const void* Wm = d_in[2];
    const void* bm = d_in[3];
    const void* Wu = d_in[4];
    const void* bu = d_in[5];
    const void* ga = d_in[6];
    const void* be = d_in[7];

    char* ws = (char*)d_ws;
    size_t off = 0;
    __hip_bfloat16* Ps  = (__hip_bfloat16*)(ws + off); off += (size_t)ND * 2;   // 12.8 MB
    __hip_bfloat16* Pt  = (__hip_bfloat16*)(ws + off); off += (size_t)ND * 2;   // 12.8 MB
    __hip_bfloat16* Msg = (__hip_bfloat16*)(ws + off); off += (size_t)ND * 2;   // 12.8 MB
    int*   BktE   = (int*)(ws + off); off += (size_t)NEDGES * 4;                // 6.4 MB
    int*   CsrSrc = (int*)(ws + off); off += (size_t)NEDGES * 4;                // 6.4 MB
    int*   Row    = (int*)(ws + off); off += (size_t)(NNODES + 1) * 4;
    int*   BktCnt = (int*)(ws + off); off += NBUCK * 4;                         // memset 0
    int*   BktOff = (int*)(ws + off); off += (NBUCK + 1) * 4;
    int*   BktCur = (int*)(ws + off); off += NBUCK * 4;
    int*   flg    = (int*)(ws + off); off += 16;
    float* WfM    = (float*)(ws + off); off += 8192 * 4;
    float* WfU    = (float*)(ws + off); off += 8192 * 4;
    float* prm    = (float*)(ws + off); off += 256 * 4;

    (void)hipMemsetAsync(BktCnt, 0, NBUCK * 4, stream);

    detect_k<<<1, 256, 0, stream>>>((const unsigned short*)x, (const unsigned int*)ei, flg);
    wconv_k<<<65, 256, 0, stream>>>(flg, Wm, Wu, bm, bu, ga, be, WfM, WfU, prm);

    proj_k<<<(NNODES + 255) / 256, 256, 0, stream>>>(flg, x, WfM, prm, Ps, Pt);

    bhist_k<<<256, 256, 0, stream>>>(flg, ei, BktCnt);
    bscan_k<<<1, 1024, 0, stream>>>(BktCnt, BktOff, BktCur);
    bfill_k<<<128, 256, 0, stream>>>(flg, ei, BktCur, BktE);
    tsort_k<<<NBUCK, 256, 0, stream>>>(BktOff, BktE, CsrSrc, Row);

    agg_k<<<(NCHUNK + 3) / 4, 256, 0, stream>>>(Ps, Pt, Row, CsrSrc, Msg);

    upd_k<<<(NNODES + 255) / 256, 256, 0, stream>>>(flg, x, Msg, WfU, prm, d_out);
}

// Round 4
// 338.791 us; speedup vs baseline: 1.1074x; 1.0797x over previous
//
#include <hip/hip_runtime.h>
#include <hip/hip_bf16.h>
#include <stdint.h>

#define NNODES 100000
#define DF 64
#define NEDGES 1600000
#define ND (NNODES * DF)     // 6,400,000
#define BKT 100              // targets per bucket
#define NBUCK 1000           // BKT*NBUCK == NNODES
#define CHUNK 128            // edges per wave in agg_k
#define NCHUNK (NEDGES / CHUNK)   // 12500

// ---------- helpers ----------
static __device__ __forceinline__ float bf2f(unsigned short u) {
    union { uint32_t i; float f; } c; c.i = ((uint32_t)u) << 16; return c.f;
}
static __device__ __forceinline__ void unpack2(uint32_t u, float& lo, float& hi) {
    union { uint32_t i; float f; } a, b;
    a.i = u << 16; b.i = u & 0xFFFF0000u;
    lo = a.f; hi = b.f;
}

// ---------- dtype detector: flags[0]=bf16?, flags[1]=int64? ----------
__global__ void detect_k(const unsigned short* __restrict__ x,
                         const unsigned int* __restrict__ ei,
                         int* __restrict__ flags) {
    __shared__ int cnt_sane, cnt_odd_nz;
    if (threadIdx.x == 0) { cnt_sane = 0; cnt_odd_nz = 0; }
    __syncthreads();
    unsigned short s = x[threadIdx.x * 2];
    unsigned short m = s & 0x7FFF;
    if (m < 0x0080 || (m >= 0x3000 && m <= 0x4200)) atomicAdd(&cnt_sane, 1);
    if (threadIdx.x < 64) {
        if (ei[threadIdx.x * 2 + 1] != 0u) atomicAdd(&cnt_odd_nz, 1);
    }
    __syncthreads();
    if (threadIdx.x == 0) {
        flags[0] = (cnt_sane >= 192) ? 1 : 0;
        flags[1] = (cnt_odd_nz == 0) ? 1 : 0;
    }
}

// ---------- weight canonicalization -> fp32 TRANSPOSED ----------
// WfMT layout: [half][k][j] : half 0 = Wm_s, half 1 = Wm_t ; element = W[j][k]
// WfUT layout: half 0 = Wu_x, half 1 = Wu_m
// prm: [0:64)=b_msg [64:128)=b_upd [128:192)=gamma [192:256)=beta [256:320)=0
__global__ void wconv_k(const int* __restrict__ flags,
                        const void* __restrict__ Wm, const void* __restrict__ Wu,
                        const void* __restrict__ bm, const void* __restrict__ bu,
                        const void* __restrict__ ga, const void* __restrict__ be,
                        float* __restrict__ WfMT, float* __restrict__ WfUT,
                        float* __restrict__ prm) {
    const int bf = flags[0];
    int i = blockIdx.x * 256 + threadIdx.x;
    if (i < 16384) {
        const void* src = (i < 8192) ? Wm : Wu;
        float* dst = (i < 8192) ? WfMT : WfUT;
        int ii = i & 8191, j = ii >> 6, k = ii & 63;
        int si = (j & 63) * 128 + ((j >> 6) ? 64 : 0) + k;
        float v = bf ? bf2f(((const unsigned short*)src)[si]) : ((const float*)src)[si];
        dst[(j >> 6) * 4096 + k * 64 + (j & 63)] = v;
    } else if (i < 16384 + 320) {
        int t = i - 16384, which = t >> 6, k = t & 63;
        if (which == 4) { prm[t] = 0.f; }
        else {
            const void* p = (which == 0) ? bm : (which == 1) ? bu : (which == 2) ? ga : be;
            prm[t] = bf ? bf2f(((const unsigned short*)p)[k]) : ((const float*)p)[k];
        }
    }
}

// ---------- generic row-matmul: out[n][j] = sum_k in[n][k] * WT[k][j] + bias[j] ----------
// wave = node (grid-stride), lane = output dim j. Weights in 64 registers per lane.
// of=1 -> fp32 output, of=0 -> bf16 output.
__global__ __launch_bounds__(256, 1) void mm_k(const int* __restrict__ flags,
                                               const void* __restrict__ xv,
                                               const float* __restrict__ WT,
                                               const float* __restrict__ bias,
                                               void* __restrict__ outv,
                                               int of) {
    const int lane = threadIdx.x & 63;
    const int wib = __builtin_amdgcn_readfirstlane(threadIdx.x >> 6);
    const int bf = flags[0];

    float w[64];
    #pragma unroll
    for (int k = 0; k < 64; ++k) w[k] = WT[k * 64 + lane];
    const float bs = bias[lane];

    const int wv = blockIdx.x * 4 + wib;
    const int nw = gridDim.x * 4;
    for (int n = wv; n < NNODES; n += nw) {
        float a0 = 0.f, a1 = 0.f, a2 = 0.f, a3 = 0.f;
        if (bf) {
            const uint4* xr = (const uint4*)((const unsigned short*)xv + (size_t)n * DF);
            #pragma unroll
            for (int q = 0; q < 8; ++q) {
                uint4 v = xr[q];
                float x0,x1,x2,x3,x4,x5,x6,x7;
                unpack2(v.x, x0, x1); unpack2(v.y, x2, x3);
                unpack2(v.z, x4, x5); unpack2(v.w, x6, x7);
                a0 = fmaf(x0, w[8*q+0], a0); a1 = fmaf(x1, w[8*q+1], a1);
                a2 = fmaf(x2, w[8*q+2], a2); a3 = fmaf(x3, w[8*q+3], a3);
                a0 = fmaf(x4, w[8*q+4], a0); a1 = fmaf(x5, w[8*q+5], a1);
                a2 = fmaf(x6, w[8*q+6], a2); a3 = fmaf(x7, w[8*q+7], a3);
            }
        } else {
            const float4* xr = (const float4*)((const float*)xv + (size_t)n * DF);
            #pragma unroll
            for (int q = 0; q < 16; ++q) {
                float4 v = xr[q];
                a0 = fmaf(v.x, w[4*q+0], a0); a1 = fmaf(v.y, w[4*q+1], a1);
                a2 = fmaf(v.z, w[4*q+2], a2); a3 = fmaf(v.w, w[4*q+3], a3);
            }
        }
        float r = (a0 + a1) + (a2 + a3) + bs;
        size_t gi = (size_t)n * DF + lane;
        if (of) ((float*)outv)[gi] = r;
        else    ((__hip_bfloat16*)outv)[gi] = __float2bfloat16(r);
    }
}

// ---------- bucket histogram (LDS pre-aggregated) ----------
__global__ __launch_bounds__(256) void bhist_k(const int* __restrict__ flags,
                                               const int* __restrict__ ei,
                                               int* __restrict__ BktCnt) {
    __shared__ int h[NBUCK];
    const int i64 = flags[1];
    for (int i = threadIdx.x; i < NBUCK; i += 256) h[i] = 0;
    __syncthreads();
    int stride = gridDim.x * 256;
    for (int e = blockIdx.x * 256 + threadIdx.x; e < NEDGES; e += stride) {
        int tgt = i64 ? ei[4*e + 2] : ei[2*e + 1];
        if ((unsigned)tgt < NNODES) atomicAdd(&h[tgt / BKT], 1);
    }
    __syncthreads();
    for (int b = threadIdx.x; b < NBUCK; b += 256)
        if (h[b]) atomicAdd(BktCnt + b, h[b]);
}

// ---------- scan of 1000 bucket counts ----------
__global__ __launch_bounds__(1024) void bscan_k(const int* __restrict__ BktCnt,
                                                int* __restrict__ BktOff,
                                                int* __restrict__ BktCur) {
    __shared__ int lds[1024];
    int t = threadIdx.x;
    int c = (t < NBUCK) ? BktCnt[t] : 0;
    lds[t] = c;
    __syncthreads();
    for (int off = 1; off < 1024; off <<= 1) {
        int add = (t >= off) ? lds[t - off] : 0;
        __syncthreads();
        lds[t] += add;
        __syncthreads();
    }
    if (t < NBUCK) {
        int ex = lds[t] - c;
        BktOff[t] = ex;
        BktCur[t] = ex;
    }
    if (t == NBUCK - 1) BktOff[NBUCK] = lds[t];
}

// ---------- bucket fill: two-pass binning, packed (tl<<24 | src) ----------
__global__ __launch_bounds__(256) void bfill_k(const int* __restrict__ flags,
                                               const int* __restrict__ ei,
                                               int* __restrict__ BktCur,
                                               int* __restrict__ BktE) {
    __shared__ int h[NBUCK], h2[NBUCK], basee[NBUCK];
    const int i64 = flags[1];
    for (int i = threadIdx.x; i < NBUCK; i += 256) { h[i] = 0; h2[i] = 0; }
    __syncthreads();
    const int stride = gridDim.x * 256;
    for (int e = blockIdx.x * 256 + threadIdx.x; e < NEDGES; e += stride) {
        int tgt = i64 ? ei[4*e + 2] : ei[2*e + 1];
        if ((unsigned)tgt < NNODES) atomicAdd(&h[tgt / BKT], 1);
    }
    __syncthreads();
    for (int b = threadIdx.x; b < NBUCK; b += 256)
        if (h[b]) basee[b] = atomicAdd(BktCur + b, h[b]);
    __syncthreads();
    for (int e = blockIdx.x * 256 + threadIdx.x; e < NEDGES; e += stride) {
        int src, tgt;
        if (i64) { src = ei[4*e]; tgt = ei[4*e + 2]; }
        else     { src = ei[2*e]; tgt = ei[2*e + 1]; }
        if ((unsigned)tgt >= NNODES) continue;
        int b = tgt / BKT;
        int tl = tgt - b * BKT;
        int r = atomicAdd(&h2[b], 1);
        BktE[basee[b] + r] = (tl << 24) | (src & 0xFFFFFF);
    }
}

// ---------- per-bucket counting sort by target -> CsrSrc + Row ----------
__global__ __launch_bounds__(256) void tsort_k(const int* __restrict__ BktOff,
                                               const int* __restrict__ BktE,
                                               int* __restrict__ CsrSrc,
                                               int* __restrict__ Row) {
    __shared__ int oc[128], excl[128], cur[128];
    const int tid = threadIdx.x;
    const int b = blockIdx.x;
    const int s = BktOff[b], e = BktOff[b + 1];
    const int n = e - s;
    if (tid < 128) { oc[tid] = 0; }
    __syncthreads();
    for (int i = tid; i < n; i += 256)
        atomicAdd(&oc[((unsigned)BktE[s + i]) >> 24], 1);
    __syncthreads();
    if (tid < 128) excl[tid] = (tid > 0) ? oc[tid - 1] : 0;
    __syncthreads();
    for (int off = 1; off < 128; off <<= 1) {
        int add = (tid >= off && tid < 128) ? excl[tid - off] : 0;
        __syncthreads();
        if (tid < 128) excl[tid] += add;
        __syncthreads();
    }
    if (tid < BKT) {
        Row[b * BKT + tid] = s + excl[tid];
        cur[tid] = excl[tid];
    }
    if (b == 0 && tid == 0) Row[NNODES] = NEDGES;
    __syncthreads();
    for (int i = tid; i < n; i += 256) {
        int v = BktE[s + i];
        int tl = ((unsigned)v) >> 24;
        int p = atomicAdd(&cur[tl], 1);
        CsrSrc[s + p] = v & 0xFFFFFF;
    }
}

// ---------- aggregation: target-aligned chunks, register accumulate ----------
__global__ __launch_bounds__(256) void agg_k(const __hip_bfloat16* __restrict__ Ps,
                                             const __hip_bfloat16* __restrict__ Pt,
                                             const int* __restrict__ Row,
                                             const int* __restrict__ CsrSrc,
                                             __hip_bfloat16* __restrict__ Msg) {
    const int lane = threadIdx.x & 63;
    const int wib = __builtin_amdgcn_readfirstlane(threadIdx.x >> 6);
    const int w = blockIdx.x * 4 + wib;
    if (w >= NCHUNK) return;
    const int eA = w * CHUNK;
    const int hiB = (w == NCHUNK - 1) ? (NEDGES + 1) : (eA + CHUNK);

    int lo = 0, hi = NNODES + 1;
    while (lo < hi) { int mid = (lo + hi) >> 1; if (Row[mid] >= eA) hi = mid; else lo = mid + 1; }
    const int t_lo = lo;
    lo = t_lo; hi = NNODES + 1;
    while (lo < hi) { int mid = (lo + hi) >> 1; if (Row[mid] >= hiB) hi = mid; else lo = mid + 1; }
    int t_hi = lo;
    if (t_hi > NNODES) t_hi = NNODES;

    const unsigned short* Ps16 = (const unsigned short*)Ps;
    const unsigned short* Pt16 = (const unsigned short*)Pt;

    for (int t = t_lo; t < t_hi; ++t) {
        const int segS = Row[t], segE = Row[t + 1];
        const int deg = segE - segS;
        float pt = bf2f(Pt16[(size_t)t * DF + lane]);
        float macc = 0.f;
        int i = segS;
        for (; i + 8 <= segE; i += 8) {
            int s0 = CsrSrc[i+0], s1 = CsrSrc[i+1], s2 = CsrSrc[i+2], s3 = CsrSrc[i+3];
            int s4 = CsrSrc[i+4], s5 = CsrSrc[i+5], s6 = CsrSrc[i+6], s7 = CsrSrc[i+7];
            if ((unsigned)s0 >= NNODES) s0 = 0;
            if ((unsigned)s1 >= NNODES) s1 = 0;
            if ((unsigned)s2 >= NNODES) s2 = 0;
            if ((unsigned)s3 >= NNODES) s3 = 0;
            if ((unsigned)s4 >= NNODES) s4 = 0;
            if ((unsigned)s5 >= NNODES) s5 = 0;
            if ((unsigned)s6 >= NNODES) s6 = 0;
            if ((unsigned)s7 >= NNODES) s7 = 0;
            float p0 = bf2f(Ps16[(size_t)s0 * DF + lane]);
            float p1 = bf2f(Ps16[(size_t)s1 * DF + lane]);
            float p2 = bf2f(Ps16[(size_t)s2 * DF + lane]);
            float p3 = bf2f(Ps16[(size_t)s3 * DF + lane]);
            float p4 = bf2f(Ps16[(size_t)s4 * DF + lane]);
            float p5 = bf2f(Ps16[(size_t)s5 * DF + lane]);
            float p6 = bf2f(Ps16[(size_t)s6 * DF + lane]);
            float p7 = bf2f(Ps16[(size_t)s7 * DF + lane]);
            macc += fmaxf(p0 + pt, 0.f) + fmaxf(p1 + pt, 0.f)
                  + fmaxf(p2 + pt, 0.f) + fmaxf(p3 + pt, 0.f)
                  + fmaxf(p4 + pt, 0.f) + fmaxf(p5 + pt, 0.f)
                  + fmaxf(p6 + pt, 0.f) + fmaxf(p7 + pt, 0.f);
        }
        for (; i < segE; ++i) {
            int s0 = CsrSrc[i];
            if ((unsigned)s0 >= NNODES) s0 = 0;
            macc += fmaxf(bf2f(Ps16[(size_t)s0 * DF + lane]) + pt, 0.f);
        }
        float mval = (deg > 0) ? (macc / (float)deg) : 0.f;
        Msg[(size_t)t * DF + lane] = __float2bfloat16(mval);
    }
}

// ---------- u2: r = relu(t1 + Msg@Wu_m^T) + x ; LayerNorm ; out ----------
// wave = node, lane = dim. Only Wu_m (64 floats) in registers.
__global__ __launch_bounds__(256, 1) void u2_k(const int* __restrict__ flags,
                                               const void* __restrict__ xv,
                                               const __hip_bfloat16* __restrict__ Msg,
                                               const float* __restrict__ t1,
                                               const float* __restrict__ WT,
                                               const float* __restrict__ prm,
                                               void* __restrict__ outv) {
    const int lane = threadIdx.x & 63;
    const int wib = __builtin_amdgcn_readfirstlane(threadIdx.x >> 6);
    const int bf = flags[0];

    float w[64];
    #pragma unroll
    for (int k = 0; k < 64; ++k) w[k] = WT[k * 64 + lane];
    const float ga = prm[128 + lane];
    const float be = prm[192 + lane];

    const unsigned short* x16 = (const unsigned short*)xv;
    const float* xf = (const float*)xv;

    const int wv = blockIdx.x * 4 + wib;
    const int nw = gridDim.x * 4;
    for (int n = wv; n < NNODES; n += nw) {
        float b0 = 0.f, b1 = 0.f, b2 = 0.f, b3 = 0.f;
        const uint4* mw = (const uint4*)((const unsigned short*)Msg + (size_t)n * DF);
        #pragma unroll
        for (int q = 0; q < 8; ++q) {
            uint4 v = mw[q];
            float m0,m1,m2,m3,m4,m5,m6,m7;
            unpack2(v.x, m0, m1); unpack2(v.y, m2, m3);
            unpack2(v.z, m4, m5); unpack2(v.w, m6, m7);
            b0 = fmaf(m0, w[8*q+0], b0); b1 = fmaf(m1, w[8*q+1], b1);
            b2 = fmaf(m2, w[8*q+2], b2); b3 = fmaf(m3, w[8*q+3], b3);
            b0 = fmaf(m4, w[8*q+4], b0); b1 = fmaf(m5, w[8*q+5], b1);
            b2 = fmaf(m6, w[8*q+6], b2); b3 = fmaf(m7, w[8*q+7], b3);
        }
        size_t gi = (size_t)n * DF + lane;
        float t  = t1[gi];
        float xl = bf ? bf2f(x16[gi]) : xf[gi];
        float u = fmaxf((b0 + b1) + (b2 + b3) + t, 0.f);
        float r = u + xl;

        float s = r, s2 = r * r;
        #pragma unroll
        for (int m = 1; m < 64; m <<= 1) {
            s  += __shfl_xor(s, m, 64);
            s2 += __shfl_xor(s2, m, 64);
        }
        float mu  = s * (1.0f / 64.0f);
        float var = fmaxf(s2 * (1.0f / 64.0f) - mu * mu, 0.f);
        float o = (r - mu) * rsqrtf(var + 1e-5f) * ga + be;

        if (bf) ((__hip_bfloat16*)outv)[gi] = __float2bfloat16(o);
        else    ((float*)outv)[gi] = o;
    }
}

extern "C" void kernel_launch(void* const* d_in, const int* in_sizes, int n_in,
                              void* d_out, int out_size, void* d_ws, size_t ws_size,
                              hipStream_t stream) {
    const void* x  = d_in[0];
    const int*  ei = (const int*)d_in[1];
    const void* Wm = d_in[2];
    const void* bm = d_in[3];
    const void* Wu = d_in[4];
    const void* bu = d_in[5];
    const void* ga = d_in[6];
    const void* be = d_in[7];

    char* ws = (char*)d_ws;
    size_t off = 0;
    __hip_bfloat16* Ps  = (__hip_bfloat16*)(ws + off); off += (size_t)ND * 2;   // 12.8 MB
    __hip_bfloat16* Pt  = (__hip_bfloat16*)(ws + off); off += (size_t)ND * 2;   // 12.8 MB
    __hip_bfloat16* Msg = (__hip_bfloat16*)(ws + off); off += (size_t)ND * 2;   // 12.8 MB
    int*   BktE   = (int*)(ws + off); off += (size_t)NEDGES * 4;                // 6.4 MB
    int*   CsrSrc = (int*)(ws + off); off += (size_t)NEDGES * 4;                // 6.4 MB
    int*   Row    = (int*)(ws + off); off += (size_t)(NNODES + 1) * 4;
    int*   BktCnt = (int*)(ws + off); off += NBUCK * 4;                         // memset 0
    int*   BktOff = (int*)(ws + off); off += (NBUCK + 1) * 4;
    int*   BktCur = (int*)(ws + off); off += NBUCK * 4;
    int*   flg    = (int*)(ws + off); off += 16;
    float* WfMT   = (float*)(ws + off); off += 8192 * 4;
    float* WfUT   = (float*)(ws + off); off += 8192 * 4;
    float* prm    = (float*)(ws + off); off += 320 * 4;

    // t1 (fp32, 25.6 MB) reuses Ps+Pt region — valid because mm_k(t1) runs AFTER agg_k.
    float* t1 = (float*)Ps;

    (void)hipMemsetAsync(BktCnt, 0, NBUCK * 4, stream);

    detect_k<<<1, 256, 0, stream>>>((const unsigned short*)x, (const unsigned int*)ei, flg);
    wconv_k<<<65, 256, 0, stream>>>(flg, Wm, Wu, bm, bu, ga, be, WfMT, WfUT, prm);

    // Ps = x@Wm_s^T (no bias -> zero slot prm+256) ; Pt = x@Wm_t^T + b_msg
    mm_k<<<1024, 256, 0, stream>>>(flg, x, WfMT,        prm + 256, Ps, 0);
    mm_k<<<1024, 256, 0, stream>>>(flg, x, WfMT + 4096, prm,       Pt, 0);

    bhist_k<<<256, 256, 0, stream>>>(flg, ei, BktCnt);
    bscan_k<<<1, 1024, 0, stream>>>(BktCnt, BktOff, BktCur);
    bfill_k<<<128, 256, 0, stream>>>(flg, ei, BktCur, BktE);
    tsort_k<<<NBUCK, 256, 0, stream>>>(BktOff, BktE, CsrSrc, Row);

    agg_k<<<(NCHUNK + 3) / 4, 256, 0, stream>>>(Ps, Pt, Row, CsrSrc, Msg);

    // t1 = x@Wu_x^T + b_upd (fp32), overwrites Ps/Pt (now dead)
    mm_k<<<1024, 256, 0, stream>>>(flg, x, WfUT, prm + 64, t1, 1);

    u2_k<<<1024, 256, 0, stream>>>(flg, x, Msg, t1, WfUT + 4096, prm, d_out);
}